// Round 16
// baseline (162.036 us; speedup 1.0000x reference)
//
#include <hip/hip_runtime.h>
#include <stdint.h>

#define BB 4
#define TT 2048
#define CC 1024
#define HH 16
#define HD 64
#define C3 3072
#define MM (BB*TT)   // 8192 rows

typedef __bf16 bf16_t;
typedef bf16_t bf16x8 __attribute__((ext_vector_type(8)));
typedef float f32x4 __attribute__((ext_vector_type(4)));
typedef unsigned short u16;
typedef u16 u16x8 __attribute__((ext_vector_type(8)));
typedef uint32_t u32;

// f32 -> bf16 round-to-nearest-even
static __device__ __forceinline__ u16 f2bf(float f){
  u32 u = __builtin_bit_cast(u32, f);
  u32 r = (u + 0x7fffu + ((u >> 16) & 1u)) >> 16;
  return (u16)r;
}

static __device__ __forceinline__ f32x4 mfma16(bf16x8 a, bf16x8 b, f32x4 c){
  return __builtin_amdgcn_mfma_f32_16x16x32_bf16(a, b, c, 0, 0, 0);
}

typedef __attribute__((address_space(1))) void* gas_t;
typedef __attribute__((address_space(3))) void* las_t;
static __device__ __forceinline__ void gload16(const void* g, void* l){
  __builtin_amdgcn_global_load_lds((gas_t)g, (las_t)l, 16, 0, 0);
}

// ---------------- fp32 -> bf16 conversion (all three inputs, one kernel) -----
__global__ __launch_bounds__(256) void cvt_all(const float* __restrict__ x,
                                               const float* __restrict__ wi,
                                               const float* __restrict__ wo,
                                               u16* __restrict__ out){
  const int n1 = MM*CC/8, n2 = C3*CC/8, n3 = CC*CC/8;
  const int total = n1 + n2 + n3;
  int stride = gridDim.x * blockDim.x;
  for (int i = blockIdx.x * blockDim.x + threadIdx.x; i < total; i += stride){
    const float* src; int k;
    if (i < n1){ src = x; k = i; }
    else if (i < n1 + n2){ src = wi; k = i - n1; }
    else { src = wo; k = i - n1 - n2; }
    const float4* p = (const float4*)src + (size_t)k * 2;
    float4 a = p[0], b = p[1];
    u16x8 o;
    o[0]=f2bf(a.x); o[1]=f2bf(a.y); o[2]=f2bf(a.z); o[3]=f2bf(a.w);
    o[4]=f2bf(b.x); o[5]=f2bf(b.y); o[6]=f2bf(b.z); o[7]=f2bf(b.w);
    *((u16x8*)out + i) = o;
  }
}

// ---------------- bt-GEMM: C[M,N] = A[M,K] * B[N,K]^T (128², dbuf-prefetch) --
// (unchanged from R14 — measured 955-970 TF)
template<int OUTBF>
__global__ __launch_bounds__(256) void gemm_bt(const u16* __restrict__ A,
                                               const u16* __restrict__ Bm,
                                               void* __restrict__ Cp,
                                               int M, int N, int K,
                                               int nbx, int cpx){
  __shared__ u16 As[2][128*64];
  __shared__ u16 Bs[2][128*64];
  const int bid = blockIdx.x;
  const int nb = (bid & 7) * cpx + (bid >> 3);
  const int by = nb / nbx, bx = nb - by * nbx;
  const int tid  = threadIdx.x;
  const int lane = tid & 63;
  const int w    = tid >> 6;
  const int m0   = by * 128;
  const int n0   = bx * 128;
  const int wm   = (w >> 1) * 64;
  const int wn   = (w & 1) * 64;
  const int lr   = lane & 15;
  const int lg4  = lane >> 4;        // 0..3

  f32x4 acc[4][4] = {};

  const int rq  = tid >> 3;                          // 0..31
  const int c8s = ((tid & 7) ^ (rq & 7)) * 8;        // pre-swizzled global col
  const u16* gA = A  + (size_t)(m0 + rq) * K + c8s;
  const u16* gB = Bm + (size_t)(n0 + rq) * K + c8s;

  auto stage = [&](int buf, int t){
    char* lA = (char*)&As[buf][0] + tid*16;
    char* lB = (char*)&Bs[buf][0] + tid*16;
    #pragma unroll
    for (int q = 0; q < 4; q++){
      gload16(gA + (size_t)(q*32)*K + t*64, lA + q*4096);
      gload16(gB + (size_t)(q*32)*K + t*64, lB + q*4096);
    }
  };

  stage(0, 0);

  const int NT = K >> 6;
  for (int t = 0; t < NT; t++){
    const int c = t & 1;
    asm volatile("s_waitcnt vmcnt(0)" ::: "memory");  // tile-t loads landed
    __builtin_amdgcn_s_barrier();                     // visible to all waves
    __builtin_amdgcn_sched_barrier(0);
    if (t + 1 < NT) stage(c ^ 1, t + 1);              // full tile to land
    #pragma unroll
    for (int kk = 0; kk < 2; kk++){
      bf16x8 af[4], bfr[4];
      #pragma unroll
      for (int m = 0; m < 4; m++){
        int row = wm + m*16 + lr;
        int slot = ((kk<<2) | lg4) ^ (row & 7);
        af[m] = *(const bf16x8*)((const char*)&As[c][0] + row*128 + slot*16);
      }
      #pragma unroll
      for (int n = 0; n < 4; n++){
        int row = wn + n*16 + lr;
        int slot = ((kk<<2) | lg4) ^ (row & 7);
        bfr[n] = *(const bf16x8*)((const char*)&Bs[c][0] + row*128 + slot*16);
      }
      __builtin_amdgcn_s_setprio(1);
      #pragma unroll
      for (int m = 0; m < 4; m++)
        #pragma unroll
        for (int n = 0; n < 4; n++)
          acc[m][n] = mfma16(af[m], bfr[n], acc[m][n]);
      __builtin_amdgcn_s_setprio(0);
    }
    __builtin_amdgcn_s_barrier();   // all reads of buf c done before overwrite
  }

  const int cr = lg4 * 4;
  #pragma unroll
  for (int m = 0; m < 4; m++)
    #pragma unroll
    for (int n = 0; n < 4; n++)
      #pragma unroll
      for (int j = 0; j < 4; j++){
        size_t row = (size_t)(m0 + wm + m*16 + cr + j);
        size_t col = (size_t)(n0 + wn + n*16 + lr);
        if (OUTBF) ((u16*)Cp)[row*(size_t)N + col] = f2bf(acc[m][n][j]);
        else       ((float*)Cp)[row*(size_t)N + col] = acc[m][n][j];
      }
}

// ---------------- flash attention (causal), bf16 in/out ----------------
// R15 structure + SADDR addressing diet: K/V global accesses use block-
// uniform base pointers (SGPR) + 32-bit per-lane offsets (kOff/vOff) so the
// compiler drops the per-lane 64-bit pointer pairs -> fits 64 arch VGPRs
// without spill at the 128-total bracket (4 blocks/CU).
__global__ __launch_bounds__(256, 4) void attn_fwd(const u16* __restrict__ qkv,
                                                   u16* __restrict__ y){
  __shared__ u16 Kl[2][64*64];   // K tile [k][64], 128B rows, slot-XOR swizzle
  __shared__ u16 Vt[2][64*72];   // V^T tile [d][k], row stride 72, dc-swizzled
  const int bid = blockIdx.x;
  const int tq = bid >> 6;
  const int h = bid & 15, b = (bid >> 4) & 3;
  const int tid = threadIdx.x, lane = tid & 63, w = tid >> 6;
  const int lr = lane & 15, lg = lane >> 4;
  const size_t base = (size_t)b * TT * C3;
  const int qA = tq*64 + w*16;          // m=0 wave q-base
  const int qB = (31-tq)*64 + w*16;     // m=1 wave q-base
  const float SC = 0.18033688011112042f;   // (1/8) * log2(e)

  // Q fragments (B-operand), pre-scaled by SC
  bf16x8 qf[2][2];
  {
    const u16* qp0 = qkv + base + (size_t)(qA + lr) * C3 + h*HD;
    qf[0][0] = *(const bf16x8*)(qp0 + lg*8);
    qf[0][1] = *(const bf16x8*)(qp0 + 32 + lg*8);
    const u16* qp1 = qkv + base + (size_t)(qB + lr) * C3 + h*HD;
    qf[1][0] = *(const bf16x8*)(qp1 + lg*8);
    qf[1][1] = *(const bf16x8*)(qp1 + 32 + lg*8);
    #pragma unroll
    for (int m = 0; m < 2; m++)
      #pragma unroll
      for (int i = 0; i < 2; i++)
        #pragma unroll
        for (int e = 0; e < 8; e++)
          qf[m][i][e] = (bf16_t)((float)qf[m][i][e] * SC);
  }

  // Uniform bases (SGPR) + 32-bit per-lane offsets (VGPR)
  const u16* gKb = qkv + base + CC   + h*HD;    // block-uniform
  const u16* gVb = qkv + base + 2*CC + h*HD;    // block-uniform
  const int rq  = tid >> 3;                       // 0..31
  const int c8k = ((tid & 7) ^ (rq & 7)) * 8;     // pre-swizzled global col
  const int kOff  = rq * C3 + c8k;                // per-lane 32-bit
  const int kOff2 = kOff + 32 * C3;
  const int rp = tid & 15;            // k-pair: rows 2rp, 2rp+1
  const int dc = (tid >> 4) & 7;      // d-chunk
  const int hf = tid >> 7;            // +32 k half
  const int vOff  = (2*rp + 32*hf) * C3 + dc*8;   // per-lane 32-bit
  const int vOff2 = vOff + C3;
  // V^T col: dc-XOR plus bank-bit-4 spread (32*(dc&1))
  const int vcol = ((2*rp + 32*hf) ^ (8*dc)) ^ (32*(dc & 1));

  auto stageK = [&](int buf, int kt1){
    const u16* g0 = gKb + (size_t)(kt1*64) * C3;   // uniform part
    gload16(g0 + kOff,  (char*)&Kl[buf][0] + tid*16);
    gload16(g0 + kOff2, (char*)&Kl[buf][0] + 4096 + tid*16);
  };

  // kb read geometry: row rho(n,lr); rbase from lr
  const int rbase = 8*(lr >> 2) + (lr & 3);

  u16x8 vreg[2];
  vreg[0] = *(const u16x8*)(gVb + vOff);
  vreg[1] = *(const u16x8*)(gVb + vOff2);
  stageK(0, 0);

  f32x4 o[2][4] = {};
  float mj[2] = {-1e30f, -1e30f};
  float lj[2] = {0.f, 0.f};

  const int ktmax = 31 - tq;
  for (int kt = 0; kt <= ktmax; kt++){
    const int cb = kt & 1;
    const u16* KL = Kl[cb];
    u16* VT = Vt[cb];
    // stage V (regs -> LDS transpose); K gloads for this tile drain at barrier
    #pragma unroll
    for (int e = 0; e < 8; e++){
      u32 pk = (u32)vreg[0][e] | ((u32)vreg[1][e] << 16);
      *(u32*)&VT[(dc*8+e)*72 + vcol] = pk;
    }
    __syncthreads();

    // prefetch next tile: K via async gload into other buffer, V into regs
    if (kt < ktmax){
      stageK(cb ^ 1, kt + 1);
      const u16* gv2 = gVb + (size_t)((kt+1)*64) * C3;   // uniform part
      vreg[0] = *(const u16x8*)(gv2 + vOff);
      vreg[1] = *(const u16x8*)(gv2 + vOff2);
    }

    const bool m0act = (kt <= tq);

    // sequential per-m: {QK, softmax, PV}
    #pragma unroll
    for (int m = 1; m >= 0; m--){
      if (m == 0 && !m0act) continue;

      // S^T via permuted K-rows: lane holds S[q=lr][k=32(n>>1)+8lg+4(n&1)+j]
      f32x4 s[4] = {};
      __builtin_amdgcn_s_setprio(1);
      #pragma unroll
      for (int n = 0; n < 4; n++){
        const int rho = 32*(n>>1) + 4*(n&1) + rbase;
        const int rk = rho & 7;
        bf16x8 kb0 = *(const bf16x8*)((const char*)KL + rho*128 + ((lg     ^ rk)*16));
        bf16x8 kb1 = *(const bf16x8*)((const char*)KL + rho*128 + (((4+lg) ^ rk)*16));
        s[n] = mfma16(kb0, qf[m][0], s[n]);
        s[n] = mfma16(kb1, qf[m][1], s[n]);
      }
      __builtin_amdgcn_s_setprio(0);

      // online softmax (scores pre-scaled): mask in place, tree reduce
      const int qrow = (m ? qB : qA) + lr;
      const bool dm = (kt == (m ? ktmax : tq));   // diagonal tile for this m
      if (dm){
        #pragma unroll
        for (int n = 0; n < 4; n++)
          #pragma unroll
          for (int j = 0; j < 4; j++)
            if (kt*64 + 32*(n>>1) + 8*lg + 4*(n&1) + j > qrow)
              s[n][j] = -1e30f;
      }
      float x0 = fmaxf(fmaxf(s[0][0], s[0][1]), fmaxf(s[0][2], s[0][3]));
      float x1 = fmaxf(fmaxf(s[1][0], s[1][1]), fmaxf(s[1][2], s[1][3]));
      float x2 = fmaxf(fmaxf(s[2][0], s[2][1]), fmaxf(s[2][2], s[2][3]));
      float x3 = fmaxf(fmaxf(s[3][0], s[3][1]), fmaxf(s[3][2], s[3][3]));
      float tm = fmaxf(fmaxf(x0, x1), fmaxf(x2, x3));
      tm = fmaxf(tm, __shfl_xor(tm, 16, 64));
      tm = fmaxf(tm, __shfl_xor(tm, 32, 64));
      float mo = mj[m];
      if (!__all(tm <= mo + 4.0f)){   // T13 defer-max, THR=4 (P <= 16)
        float mn = fmaxf(mo, tm);
        float al = __builtin_amdgcn_exp2f(mo - mn);
        mj[m] = mn;
        lj[m] *= al;
        float a0 = __shfl(al, lg*4+0, 16);
        float a1 = __shfl(al, lg*4+1, 16);
        float a2 = __shfl(al, lg*4+2, 16);
        float a3 = __shfl(al, lg*4+3, 16);
        #pragma unroll
        for (int n = 0; n < 4; n++){
          o[m][n][0] *= a0; o[m][n][1] *= a1;
          o[m][n][2] *= a2; o[m][n][3] *= a3;
        }
      }
      float mm = mj[m];
      float psn[4];
      bf16x8 pa, pb;
      #pragma unroll
      for (int n = 0; n < 4; n++){
        float p0 = __builtin_amdgcn_exp2f(s[n][0] - mm);
        float p1 = __builtin_amdgcn_exp2f(s[n][1] - mm);
        float p2 = __builtin_amdgcn_exp2f(s[n][2] - mm);
        float p3 = __builtin_amdgcn_exp2f(s[n][3] - mm);
        psn[n] = (p0 + p1) + (p2 + p3);
        if (n == 0){ pa[0]=(bf16_t)p0; pa[1]=(bf16_t)p1; pa[2]=(bf16_t)p2; pa[3]=(bf16_t)p3; }
        if (n == 1){ pa[4]=(bf16_t)p0; pa[5]=(bf16_t)p1; pa[6]=(bf16_t)p2; pa[7]=(bf16_t)p3; }
        if (n == 2){ pb[0]=(bf16_t)p0; pb[1]=(bf16_t)p1; pb[2]=(bf16_t)p2; pb[3]=(bf16_t)p3; }
        if (n == 3){ pb[4]=(bf16_t)p0; pb[5]=(bf16_t)p1; pb[6]=(bf16_t)p2; pb[7]=(bf16_t)p3; }
      }
      float ps = (psn[0] + psn[1]) + (psn[2] + psn[3]);
      ps += __shfl_xor(ps, 16, 64);
      ps += __shfl_xor(ps, 32, 64);
      lj[m] += ps;

      // O[m] += P V  (V^T fragments just-in-time from LDS)
      __builtin_amdgcn_s_setprio(1);
      #pragma unroll
      for (int n = 0; n < 4; n++){
        const int dcr = (2*n + (lr >> 3)) & 7;
        const int c0 = ((lg ^ dcr) ^ (4 * (dcr & 1))) * 8;
        bf16x8 vb0 = *(const bf16x8*)&VT[(n*16+lr)*72 + c0];
        bf16x8 vb1 = *(const bf16x8*)&VT[(n*16+lr)*72 + (c0 ^ 32)];
        o[m][n] = mfma16(pa, vb0, o[m][n]);
        o[m][n] = mfma16(pb, vb1, o[m][n]);
      }
      __builtin_amdgcn_s_setprio(0);
    }
  }

  // normalize + write y (bf16); 1/l transposed to o's row layout via shfl
  #pragma unroll
  for (int m = 0; m < 2; m++){
    float inv = 1.0f / lj[m];
    float i0 = __shfl(inv, lg*4+0, 16);
    float i1 = __shfl(inv, lg*4+1, 16);
    float i2 = __shfl(inv, lg*4+2, 16);
    float i3 = __shfl(inv, lg*4+3, 16);
    const int qb = (m ? qB : qA);
    #pragma unroll
    for (int j = 0; j < 4; j++){
      float ij = (j==0) ? i0 : (j==1) ? i1 : (j==2) ? i2 : i3;
      size_t row = (size_t)b*TT + qb + lg*4 + j;
      #pragma unroll
      for (int n = 0; n < 4; n++)
        y[row*CC + h*HD + n*16 + lr] = f2bf(o[m][n][j] * ij);
    }
  }
}

// ---------------- launch ----------------
extern "C" void kernel_launch(void* const* d_in, const int* in_sizes, int n_in,
                              void* d_out, int out_size, void* d_ws, size_t ws_size,
                              hipStream_t stream){
  const float* x     = (const float*)d_in[0];
  const float* w_in  = (const float*)d_in[1];
  const float* w_out = (const float*)d_in[2];
  float* out = (float*)d_out;

  u16* xb   = (u16*)d_ws;                  // 8192*1024  (reused as y after GEMM1)
  u16* wib  = xb  + (size_t)MM * CC;       // 3072*1024
  u16* wob  = wib + (size_t)C3 * CC;       // 1024*1024
  u16* qkvb = wob + (size_t)CC * CC;       // 8192*3072
  u16* yb   = xb;                          // x is dead after GEMM1

  cvt_all<<<2048, 256, 0, stream>>>(x, w_in, w_out, xb);

  // GEMM1: 8192x3072x1024 -> grid 64x24 = 1536 blocks of 128², 192/XCD
  gemm_bt<1><<<1536, 256, 0, stream>>>(xb, wib, (void*)qkvb, MM, C3, CC, 24, 192);
  attn_fwd<<<1024, 256, 0, stream>>>(qkvb, yb);
  // GEMM2: 8192x1024x1024 -> grid 64x8 = 512 blocks of 128², 64/XCD
  gemm_bt<0><<<512, 256, 0, stream>>>(yb, wob, (void*)out, MM, CC, CC, 8, 64);
}

// Round 17
// 160.762 us; speedup vs baseline: 1.0079x; 1.0079x over previous
//
#include <hip/hip_runtime.h>
#include <stdint.h>

#define BB 4
#define TT 2048
#define CC 1024
#define HH 16
#define HD 64
#define C3 3072
#define MM (BB*TT)   // 8192 rows

typedef __bf16 bf16_t;
typedef bf16_t bf16x8 __attribute__((ext_vector_type(8)));
typedef float f32x4 __attribute__((ext_vector_type(4)));
typedef unsigned short u16;
typedef u16 u16x8 __attribute__((ext_vector_type(8)));
typedef uint32_t u32;

// f32 -> bf16 round-to-nearest-even
static __device__ __forceinline__ u16 f2bf(float f){
  u32 u = __builtin_bit_cast(u32, f);
  u32 r = (u + 0x7fffu + ((u >> 16) & 1u)) >> 16;
  return (u16)r;
}

static __device__ __forceinline__ f32x4 mfma16(bf16x8 a, bf16x8 b, f32x4 c){
  return __builtin_amdgcn_mfma_f32_16x16x32_bf16(a, b, c, 0, 0, 0);
}

typedef __attribute__((address_space(1))) void* gas_t;
typedef __attribute__((address_space(3))) void* las_t;
static __device__ __forceinline__ void gload16(const void* g, void* l){
  __builtin_amdgcn_global_load_lds((gas_t)g, (las_t)l, 16, 0, 0);
}

// ---------------- fp32 -> bf16 conversion (all three inputs, one kernel) -----
__global__ __launch_bounds__(256) void cvt_all(const float* __restrict__ x,
                                               const float* __restrict__ wi,
                                               const float* __restrict__ wo,
                                               u16* __restrict__ out){
  const int n1 = MM*CC/8, n2 = C3*CC/8, n3 = CC*CC/8;
  const int total = n1 + n2 + n3;
  int stride = gridDim.x * blockDim.x;
  for (int i = blockIdx.x * blockDim.x + threadIdx.x; i < total; i += stride){
    const float* src; int k;
    if (i < n1){ src = x; k = i; }
    else if (i < n1 + n2){ src = wi; k = i - n1; }
    else { src = wo; k = i - n1 - n2; }
    const float4* p = (const float4*)src + (size_t)k * 2;
    float4 a = p[0], b = p[1];
    u16x8 o;
    o[0]=f2bf(a.x); o[1]=f2bf(a.y); o[2]=f2bf(a.z); o[3]=f2bf(a.w);
    o[4]=f2bf(b.x); o[5]=f2bf(b.y); o[6]=f2bf(b.z); o[7]=f2bf(b.w);
    *((u16x8*)out + i) = o;
  }
}

// ---------------- bt-GEMM: C[M,N] = A[M,K] * B[N,K]^T (128², dbuf-prefetch) --
// (R14 structure — measured 955-970 TF)
template<int OUTBF>
__global__ __launch_bounds__(256) void gemm_bt(const u16* __restrict__ A,
                                               const u16* __restrict__ Bm,
                                               void* __restrict__ Cp,
                                               int M, int N, int K,
                                               int nbx, int cpx){
  __shared__ u16 As[2][128*64];
  __shared__ u16 Bs[2][128*64];
  const int bid = blockIdx.x;
  const int nb = (bid & 7) * cpx + (bid >> 3);
  const int by = nb / nbx, bx = nb - by * nbx;
  const int tid  = threadIdx.x;
  const int lane = tid & 63;
  const int w    = tid >> 6;
  const int m0   = by * 128;
  const int n0   = bx * 128;
  const int wm   = (w >> 1) * 64;
  const int wn   = (w & 1) * 64;
  const int lr   = lane & 15;
  const int lg4  = lane >> 4;        // 0..3

  f32x4 acc[4][4] = {};

  const int rq  = tid >> 3;                          // 0..31
  const int c8s = ((tid & 7) ^ (rq & 7)) * 8;        // pre-swizzled global col
  const u16* gA = A  + (size_t)(m0 + rq) * K + c8s;
  const u16* gB = Bm + (size_t)(n0 + rq) * K + c8s;

  auto stage = [&](int buf, int t){
    char* lA = (char*)&As[buf][0] + tid*16;
    char* lB = (char*)&Bs[buf][0] + tid*16;
    #pragma unroll
    for (int q = 0; q < 4; q++){
      gload16(gA + (size_t)(q*32)*K + t*64, lA + q*4096);
      gload16(gB + (size_t)(q*32)*K + t*64, lB + q*4096);
    }
  };

  stage(0, 0);

  const int NT = K >> 6;
  for (int t = 0; t < NT; t++){
    const int c = t & 1;
    asm volatile("s_waitcnt vmcnt(0)" ::: "memory");  // tile-t loads landed
    __builtin_amdgcn_s_barrier();                     // visible to all waves
    __builtin_amdgcn_sched_barrier(0);
    if (t + 1 < NT) stage(c ^ 1, t + 1);              // full tile to land
    #pragma unroll
    for (int kk = 0; kk < 2; kk++){
      bf16x8 af[4], bfr[4];
      #pragma unroll
      for (int m = 0; m < 4; m++){
        int row = wm + m*16 + lr;
        int slot = ((kk<<2) | lg4) ^ (row & 7);
        af[m] = *(const bf16x8*)((const char*)&As[c][0] + row*128 + slot*16);
      }
      #pragma unroll
      for (int n = 0; n < 4; n++){
        int row = wn + n*16 + lr;
        int slot = ((kk<<2) | lg4) ^ (row & 7);
        bfr[n] = *(const bf16x8*)((const char*)&Bs[c][0] + row*128 + slot*16);
      }
      __builtin_amdgcn_s_setprio(1);
      #pragma unroll
      for (int m = 0; m < 4; m++)
        #pragma unroll
        for (int n = 0; n < 4; n++)
          acc[m][n] = mfma16(af[m], bfr[n], acc[m][n]);
      __builtin_amdgcn_s_setprio(0);
    }
    __builtin_amdgcn_s_barrier();   // all reads of buf c done before overwrite
  }

  const int cr = lg4 * 4;
  #pragma unroll
  for (int m = 0; m < 4; m++)
    #pragma unroll
    for (int n = 0; n < 4; n++)
      #pragma unroll
      for (int j = 0; j < 4; j++){
        size_t row = (size_t)(m0 + wm + m*16 + cr + j);
        size_t col = (size_t)(n0 + wn + n*16 + lr);
        if (OUTBF) ((u16*)Cp)[row*(size_t)N + col] = f2bf(acc[m][n][j]);
        else       ((float*)Cp)[row*(size_t)N + col] = acc[m][n][j];
      }
}

// ---------------- flash attention (causal), bf16 in/out ----------------
// R15 configuration (session-best): K staged via global_load_lds into a
// GEMM-style [64][64] slot-XOR LDS layout; V reg-transposed with conflict-
// free dc-swizzle; swapped QK^T with permuted K-rows (P natively packed for
// PV); sequential per-m bodies; defer-max THR=4; launch_bounds(256,4).
__global__ __launch_bounds__(256, 4) void attn_fwd(const u16* __restrict__ qkv,
                                                   u16* __restrict__ y){
  __shared__ u16 Kl[2][64*64];   // K tile [k][64], 128B rows, slot-XOR swizzle
  __shared__ u16 Vt[2][64*72];   // V^T tile [d][k], row stride 72, dc-swizzled
  const int bid = blockIdx.x;
  const int tq = bid >> 6;
  const int h = bid & 15, b = (bid >> 4) & 3;
  const int tid = threadIdx.x, lane = tid & 63, w = tid >> 6;
  const int lr = lane & 15, lg = lane >> 4;
  const size_t base = (size_t)b * TT * C3;
  const int qA = tq*64 + w*16;          // m=0 wave q-base
  const int qB = (31-tq)*64 + w*16;     // m=1 wave q-base
  const float SC = 0.18033688011112042f;   // (1/8) * log2(e)

  // Q fragments (B-operand), pre-scaled by SC
  bf16x8 qf[2][2];
  {
    const u16* qp0 = qkv + base + (size_t)(qA + lr) * C3 + h*HD;
    qf[0][0] = *(const bf16x8*)(qp0 + lg*8);
    qf[0][1] = *(const bf16x8*)(qp0 + 32 + lg*8);
    const u16* qp1 = qkv + base + (size_t)(qB + lr) * C3 + h*HD;
    qf[1][0] = *(const bf16x8*)(qp1 + lg*8);
    qf[1][1] = *(const bf16x8*)(qp1 + 32 + lg*8);
    #pragma unroll
    for (int m = 0; m < 2; m++)
      #pragma unroll
      for (int i = 0; i < 2; i++)
        #pragma unroll
        for (int e = 0; e < 8; e++)
          qf[m][i][e] = (bf16_t)((float)qf[m][i][e] * SC);
  }

  // K staging: async gload_lds, pre-swizzled source col (GEMM scheme)
  const int rq  = tid >> 3;                       // 0..31
  const int c8k = ((tid & 7) ^ (rq & 7)) * 8;     // pre-swizzled global col
  const u16* gK = qkv + base + (size_t)rq * C3 + CC + h*HD + c8k;
  // V staging: adjacent k-row pair, reg transpose
  const int rp = tid & 15;            // k-pair: rows 2rp, 2rp+1
  const int dc = (tid >> 4) & 7;      // d-chunk
  const int hf = tid >> 7;            // +32 k half
  const u16* gV = qkv + base + (size_t)(2*rp + 32*hf) * C3 + 2*CC + h*HD + dc*8;
  // V^T col: dc-XOR plus bank-bit-4 spread (32*(dc&1))
  const int vcol = ((2*rp + 32*hf) ^ (8*dc)) ^ (32*(dc & 1));

  auto stageK = [&](int buf, int kt1){
    const u16* g0 = gK + (size_t)(kt1*64) * C3;
    gload16(g0,                  (char*)&Kl[buf][0] + tid*16);
    gload16(g0 + (size_t)32*C3,  (char*)&Kl[buf][0] + 4096 + tid*16);
  };

  // kb read geometry: row rho(n,lr); rbase from lr
  const int rbase = 8*(lr >> 2) + (lr & 3);

  u16x8 vreg[2];
  vreg[0] = *(const u16x8*)(gV);
  vreg[1] = *(const u16x8*)(gV + C3);
  stageK(0, 0);

  f32x4 o[2][4] = {};
  float mj[2] = {-1e30f, -1e30f};
  float lj[2] = {0.f, 0.f};

  const int ktmax = 31 - tq;
  for (int kt = 0; kt <= ktmax; kt++){
    const int cb = kt & 1;
    const u16* KL = Kl[cb];
    u16* VT = Vt[cb];
    // stage V (regs -> LDS transpose); K gloads for this tile drain at barrier
    #pragma unroll
    for (int e = 0; e < 8; e++){
      u32 pk = (u32)vreg[0][e] | ((u32)vreg[1][e] << 16);
      *(u32*)&VT[(dc*8+e)*72 + vcol] = pk;
    }
    __syncthreads();

    // prefetch next tile: K via async gload into other buffer, V into regs
    if (kt < ktmax){
      stageK(cb ^ 1, kt + 1);
      const u16* gv2 = gV + (size_t)(kt+1)*64*C3;
      vreg[0] = *(const u16x8*)(gv2);
      vreg[1] = *(const u16x8*)(gv2 + C3);
    }

    const bool m0act = (kt <= tq);

    // sequential per-m: {QK, softmax, PV}
    #pragma unroll
    for (int m = 1; m >= 0; m--){
      if (m == 0 && !m0act) continue;

      // S^T via permuted K-rows: lane holds S[q=lr][k=32(n>>1)+8lg+4(n&1)+j]
      f32x4 s[4] = {};
      __builtin_amdgcn_s_setprio(1);
      #pragma unroll
      for (int n = 0; n < 4; n++){
        const int rho = 32*(n>>1) + 4*(n&1) + rbase;
        const int rk = rho & 7;
        bf16x8 kb0 = *(const bf16x8*)((const char*)KL + rho*128 + ((lg     ^ rk)*16));
        bf16x8 kb1 = *(const bf16x8*)((const char*)KL + rho*128 + (((4+lg) ^ rk)*16));
        s[n] = mfma16(kb0, qf[m][0], s[n]);
        s[n] = mfma16(kb1, qf[m][1], s[n]);
      }
      __builtin_amdgcn_s_setprio(0);

      // online softmax (scores pre-scaled): mask in place, tree reduce
      const int qrow = (m ? qB : qA) + lr;
      const bool dm = (kt == (m ? ktmax : tq));   // diagonal tile for this m
      if (dm){
        #pragma unroll
        for (int n = 0; n < 4; n++)
          #pragma unroll
          for (int j = 0; j < 4; j++)
            if (kt*64 + 32*(n>>1) + 8*lg + 4*(n&1) + j > qrow)
              s[n][j] = -1e30f;
      }
      float x0 = fmaxf(fmaxf(s[0][0], s[0][1]), fmaxf(s[0][2], s[0][3]));
      float x1 = fmaxf(fmaxf(s[1][0], s[1][1]), fmaxf(s[1][2], s[1][3]));
      float x2 = fmaxf(fmaxf(s[2][0], s[2][1]), fmaxf(s[2][2], s[2][3]));
      float x3 = fmaxf(fmaxf(s[3][0], s[3][1]), fmaxf(s[3][2], s[3][3]));
      float tm = fmaxf(fmaxf(x0, x1), fmaxf(x2, x3));
      tm = fmaxf(tm, __shfl_xor(tm, 16, 64));
      tm = fmaxf(tm, __shfl_xor(tm, 32, 64));
      float mo = mj[m];
      if (!__all(tm <= mo + 4.0f)){   // T13 defer-max, THR=4 (P <= 16)
        float mn = fmaxf(mo, tm);
        float al = __builtin_amdgcn_exp2f(mo - mn);
        mj[m] = mn;
        lj[m] *= al;
        float a0 = __shfl(al, lg*4+0, 16);
        float a1 = __shfl(al, lg*4+1, 16);
        float a2 = __shfl(al, lg*4+2, 16);
        float a3 = __shfl(al, lg*4+3, 16);
        #pragma unroll
        for (int n = 0; n < 4; n++){
          o[m][n][0] *= a0; o[m][n][1] *= a1;
          o[m][n][2] *= a2; o[m][n][3] *= a3;
        }
      }
      float mm = mj[m];
      float psn[4];
      bf16x8 pa, pb;
      #pragma unroll
      for (int n = 0; n < 4; n++){
        float p0 = __builtin_amdgcn_exp2f(s[n][0] - mm);
        float p1 = __builtin_amdgcn_exp2f(s[n][1] - mm);
        float p2 = __builtin_amdgcn_exp2f(s[n][2] - mm);
        float p3 = __builtin_amdgcn_exp2f(s[n][3] - mm);
        psn[n] = (p0 + p1) + (p2 + p3);
        if (n == 0){ pa[0]=(bf16_t)p0; pa[1]=(bf16_t)p1; pa[2]=(bf16_t)p2; pa[3]=(bf16_t)p3; }
        if (n == 1){ pa[4]=(bf16_t)p0; pa[5]=(bf16_t)p1; pa[6]=(bf16_t)p2; pa[7]=(bf16_t)p3; }
        if (n == 2){ pb[0]=(bf16_t)p0; pb[1]=(bf16_t)p1; pb[2]=(bf16_t)p2; pb[3]=(bf16_t)p3; }
        if (n == 3){ pb[4]=(bf16_t)p0; pb[5]=(bf16_t)p1; pb[6]=(bf16_t)p2; pb[7]=(bf16_t)p3; }
      }
      float ps = (psn[0] + psn[1]) + (psn[2] + psn[3]);
      ps += __shfl_xor(ps, 16, 64);
      ps += __shfl_xor(ps, 32, 64);
      lj[m] += ps;

      // O[m] += P V  (V^T fragments just-in-time from LDS)
      __builtin_amdgcn_s_setprio(1);
      #pragma unroll
      for (int n = 0; n < 4; n++){
        const int dcr = (2*n + (lr >> 3)) & 7;
        const int c0 = ((lg ^ dcr) ^ (4 * (dcr & 1))) * 8;
        bf16x8 vb0 = *(const bf16x8*)&VT[(n*16+lr)*72 + c0];
        bf16x8 vb1 = *(const bf16x8*)&VT[(n*16+lr)*72 + (c0 ^ 32)];
        o[m][n] = mfma16(pa, vb0, o[m][n]);
        o[m][n] = mfma16(pb, vb1, o[m][n]);
      }
      __builtin_amdgcn_s_setprio(0);
    }
  }

  // normalize + write y (bf16); 1/l transposed to o's row layout via shfl
  #pragma unroll
  for (int m = 0; m < 2; m++){
    float inv = 1.0f / lj[m];
    float i0 = __shfl(inv, lg*4+0, 16);
    float i1 = __shfl(inv, lg*4+1, 16);
    float i2 = __shfl(inv, lg*4+2, 16);
    float i3 = __shfl(inv, lg*4+3, 16);
    const int qb = (m ? qB : qA);
    #pragma unroll
    for (int j = 0; j < 4; j++){
      float ij = (j==0) ? i0 : (j==1) ? i1 : (j==2) ? i2 : i3;
      size_t row = (size_t)b*TT + qb + lg*4 + j;
      #pragma unroll
      for (int n = 0; n < 4; n++)
        y[row*CC + h*HD + n*16 + lr] = f2bf(o[m][n][j] * ij);
    }
  }
}

// ---------------- launch ----------------
extern "C" void kernel_launch(void* const* d_in, const int* in_sizes, int n_in,
                              void* d_out, int out_size, void* d_ws, size_t ws_size,
                              hipStream_t stream){
  const float* x     = (const float*)d_in[0];
  const float* w_in  = (const float*)d_in[1];
  const float* w_out = (const float*)d_in[2];
  float* out = (float*)d_out;

  u16* xb   = (u16*)d_ws;                  // 8192*1024  (reused as y after GEMM1)
  u16* wib  = xb  + (size_t)MM * CC;       // 3072*1024
  u16* wob  = wib + (size_t)C3 * CC;       // 1024*1024
  u16* qkvb = wob + (size_t)CC * CC;       // 8192*3072
  u16* yb   = xb;                          // x is dead after GEMM1

  cvt_all<<<2048, 256, 0, stream>>>(x, w_in, w_out, xb);

  // GEMM1: 8192x3072x1024 -> grid 64x24 = 1536 blocks of 128², 192/XCD
  gemm_bt<1><<<1536, 256, 0, stream>>>(xb, wib, (void*)qkvb, MM, C3, CC, 24, 192);
  attn_fwd<<<1024, 256, 0, stream>>>(qkvb, yb);
  // GEMM2: 8192x1024x1024 -> grid 64x8 = 512 blocks of 128², 64/XCD
  gemm_bt<0><<<512, 256, 0, stream>>>(yb, wob, (void*)out, MM, CC, CC, 8, 64);
}